// Round 8
// baseline (148.850 us; speedup 1.0000x reference)
//
#include <hip/hip_runtime.h>
#include <hip/hip_bf16.h>

// Single fused dispatch:
//   phase A: ph[i]=dot(x_h[i],W1[0:64]); pg[j]=dot(x_g[j],W1[64:128]) (tables)
//            sacc_e = dot(ea_e, W1[128:136]) + pu[batch_e] (registers)
//   grid barrier (RELAXED polls + ONE acquire fence -- R2 post-mortem: an
//   ACQUIRE load per poll forces an L2 invalidate per iteration on gfx950 ->
//   invalidate storm, 10x slowdown. Relaxed scoped atomics bypass the
//   non-coherent caches without the invalidate side effect.)
//   phase B: out[e] = leaky(sacc + ph[src] + pg[tgt], 0.1)*W2 + b2
// Fallback: proven two-kernel path (31 us).

#define TPB 256
#define EPT 4   // edges per thread, register-resident

typedef float f32x4 __attribute__((ext_vector_type(4)));

__device__ __forceinline__ float dot4(float4 a, float4 b) {
    return a.x * b.x + a.y * b.y + a.z * b.z + a.w * b.w;
}

__global__ void __launch_bounds__(TPB, 4)
fused_one_pass(const float* __restrict__ xh, const float* __restrict__ xg,
               const float* __restrict__ edge_attr, const float* __restrict__ u,
               const int* __restrict__ edge_index, const int* __restrict__ batch_e,
               const float* __restrict__ W1, const float* __restrict__ b1,
               const float* __restrict__ W2, const float* __restrict__ b2,
               float* __restrict__ ph, float* __restrict__ pg,
               unsigned* __restrict__ cnt,
               float* __restrict__ out,
               int nh, int ng, int ngr, int E, int nblocks) {
    __shared__ float pu_s[256];

    const int tid = blockIdx.x * TPB + threadIdx.x;
    const int NT  = nblocks * TPB;

    // pu table in LDS (ngr <= 256; host-checked)
    if ((int)threadIdx.x < ngr) {
        const float4* uv = reinterpret_cast<const float4*>(u + (size_t)threadIdx.x * 16);
        const float4* wu = reinterpret_cast<const float4*>(W1 + 136);
        float s = dot4(uv[0], wu[0]) + dot4(uv[1], wu[1])
                + dot4(uv[2], wu[2]) + dot4(uv[3], wu[3]);
        pu_s[threadIdx.x] = s + b1[0];
    }
    __syncthreads();

    // --- phase A1: node partial tables (coalesced, 16 lanes/row) ---
    {
        const int group   = tid >> 4;
        const int q       = tid & 15;
        const int ngroups = NT >> 4;
        const int total   = nh + ng;
        for (int r = group; r < total; r += ngroups) {
            const float* srcp = (r < nh) ? xh + (size_t)r * 64
                                         : xg + (size_t)(r - nh) * 64;
            const float* wp   = (r < nh) ? W1 : W1 + 64;
            float4 v  = reinterpret_cast<const float4*>(srcp)[q];
            float4 wv = reinterpret_cast<const float4*>(wp)[q];
            float s = dot4(v, wv);
            s += __shfl_xor(s, 1);
            s += __shfl_xor(s, 2);
            s += __shfl_xor(s, 4);
            s += __shfl_xor(s, 8);
            if (q == 0) {
                if (r < nh) ph[r] = s;
                else        pg[r - nh] = s;
            }
        }
    }

    // --- phase A2: per-edge partials, register-resident ---
    const float* wx = W1 + 128;
    const float w0 = wx[0], w1 = wx[1], w2 = wx[2], w3 = wx[3];
    const float w4 = wx[4], w5 = wx[5], w6 = wx[6], w7 = wx[7];

    const int base = tid * EPT;
    float sacc[EPT];
    int   sv[EPT], tv[EPT];
#pragma unroll
    for (int i = 0; i < EPT; ++i) {
        int e = base + i;
        sv[i] = 0; tv[i] = 0; sacc[i] = 0.0f;
        if (e < E) {
            sv[i] = edge_index[e];
            tv[i] = edge_index[E + e];
            int g = batch_e[e];
            const f32x4* ea = reinterpret_cast<const f32x4*>(edge_attr + (size_t)e * 8);
            f32x4 a0 = ea[0], a1 = ea[1];
            sacc[i] = pu_s[g]
                    + a0.x * w0 + a0.y * w1 + a0.z * w2 + a0.w * w3
                    + a1.x * w4 + a1.y * w5 + a1.z * w6 + a1.w * w7;
        }
    }

    // --- grid barrier: RELEASE add; RELAXED polls; ONE acquire fence ---
    __syncthreads();
    if (threadIdx.x == 0) {
        __hip_atomic_fetch_add(cnt, 1u, __ATOMIC_RELEASE, __HIP_MEMORY_SCOPE_AGENT);
        unsigned v;
        do {
            __builtin_amdgcn_s_sleep(16);
            v = __hip_atomic_load(cnt, __ATOMIC_RELAXED, __HIP_MEMORY_SCOPE_AGENT);
        } while (v < (unsigned)nblocks);
        __builtin_amdgcn_fence(__ATOMIC_ACQUIRE, "agent");
    }
    __syncthreads();

    // --- phase B: gather + finalize ---
    const float w2s = W2[0], b2s = b2[0];
    if (base + EPT <= E) {
        float pp[EPT], qq[EPT];
#pragma unroll
        for (int i = 0; i < EPT; ++i) { pp[i] = ph[sv[i]]; qq[i] = pg[tv[i]]; }
        f32x4 hv;
        float res[EPT];
#pragma unroll
        for (int i = 0; i < EPT; ++i) {
            float h = sacc[i] + pp[i] + qq[i];
            h = (h >= 0.0f) ? h : 0.1f * h;
            res[i] = h * w2s + b2s;
        }
        hv.x = res[0]; hv.y = res[1]; hv.z = res[2]; hv.w = res[3];
        *reinterpret_cast<f32x4*>(out + base) = hv;
    } else {
        for (int i = 0; i < EPT; ++i) {
            int e = base + i;
            if (e < E) {
                float h = sacc[i] + ph[sv[i]] + pg[tv[i]];
                h = (h >= 0.0f) ? h : 0.1f * h;
                out[e] = h * w2s + b2s;
            }
        }
    }
}

// ---------------- proven fallback: two-kernel path ----------------
__global__ void __launch_bounds__(TPB, 8)
precompute_partials(const float* __restrict__ xh, const float* __restrict__ xg,
                    const float* __restrict__ u, const float* __restrict__ W1,
                    const float* __restrict__ b1,
                    float* __restrict__ ph, float* __restrict__ pg,
                    float* __restrict__ pu, int nh, int ng, int ngr) {
    const int gid     = blockIdx.x * TPB + threadIdx.x;
    const int group   = gid >> 4;
    const int q       = gid & 15;
    const int ngroups = (gridDim.x * TPB) >> 4;
    const int total   = nh + ng + ngr;
    for (int r = group; r < total; r += ngroups) {
        if (r < nh + ng) {
            const float* srcp = (r < nh) ? xh + (size_t)r * 64
                                         : xg + (size_t)(r - nh) * 64;
            const float* wp   = (r < nh) ? W1 : W1 + 64;
            float4 v  = reinterpret_cast<const float4*>(srcp)[q];
            float4 wv = reinterpret_cast<const float4*>(wp)[q];
            float s = dot4(v, wv);
            s += __shfl_xor(s, 1);
            s += __shfl_xor(s, 2);
            s += __shfl_xor(s, 4);
            s += __shfl_xor(s, 8);
            if (q == 0) {
                if (r < nh) ph[r] = s;
                else        pg[r - nh] = s;
            }
        } else {
            int g = r - nh - ng;
            float s = 0.0f;
            if (q < 4) {
                float4 v  = reinterpret_cast<const float4*>(u + (size_t)g * 16)[q];
                float4 wv = reinterpret_cast<const float4*>(W1 + 136)[q];
                s = dot4(v, wv);
            }
            s += __shfl_xor(s, 1);
            s += __shfl_xor(s, 2);
            if (q == 0) pu[g] = s + b1[0];
        }
    }
}

__global__ void __launch_bounds__(TPB, 8)
edge_kernel(const int* __restrict__ edge_index, const int* __restrict__ batch_e,
            const float* __restrict__ edge_attr, const float* __restrict__ W1,
            const float* __restrict__ W2, const float* __restrict__ b2,
            const float* __restrict__ ph, const float* __restrict__ pg,
            const float* __restrict__ pu, float* __restrict__ out, int E) {
    int e = blockIdx.x * TPB + threadIdx.x;
    if (e >= E) return;
    int s = edge_index[e];
    int t = edge_index[E + e];
    int g = batch_e[e];
    const f32x4* ea = reinterpret_cast<const f32x4*>(edge_attr + (size_t)e * 8);
    f32x4 a0 = ea[0], a1 = ea[1];
    const float* wx = W1 + 128;
    float h = ph[s] + pg[t] + pu[g]
            + a0.x * wx[0] + a0.y * wx[1] + a0.z * wx[2] + a0.w * wx[3]
            + a1.x * wx[4] + a1.y * wx[5] + a1.z * wx[6] + a1.w * wx[7];
    h = (h >= 0.0f) ? h : 0.1f * h;
    out[e] = h * W2[0] + b2[0];
}

extern "C" void kernel_launch(void* const* d_in, const int* in_sizes, int n_in,
                              void* d_out, int out_size, void* d_ws, size_t ws_size,
                              hipStream_t stream) {
    const float* x_h       = (const float*)d_in[0];
    const float* x_g       = (const float*)d_in[1];
    const float* edge_attr = (const float*)d_in[2];
    const float* u         = (const float*)d_in[3];
    const int*   edge_idx  = (const int*)d_in[4];
    const int*   batch_e   = (const int*)d_in[5];
    const float* W1        = (const float*)d_in[6];
    const float* b1        = (const float*)d_in[7];
    const float* W2        = (const float*)d_in[8];
    const float* b2        = (const float*)d_in[9];
    float* out = (float*)d_out;

    const int E   = in_sizes[5];
    const int nh  = in_sizes[0] / 64;
    const int ng  = in_sizes[1] / 64;
    const int ngr = in_sizes[3] / 16;

    // ws: ph[nh] | pg[ng] | pu[ngr] (fallback) | counter
    size_t need = ((size_t)nh + ng + ngr) * sizeof(float) + sizeof(unsigned);

    int perCU = 0, numCU = 0;
    hipError_t e1 = hipOccupancyMaxActiveBlocksPerMultiprocessor(
        &perCU, reinterpret_cast<const void*>(fused_one_pass), TPB, 0);
    hipError_t e2 = hipDeviceGetAttribute(&numCU, hipDeviceAttributeMultiprocessorCount, 0);

    int needBlocks = (E + TPB * EPT - 1) / (TPB * EPT);
    bool fused_ok = (e1 == hipSuccess) && (e2 == hipSuccess) && (perCU > 0) &&
                    (numCU > 0) && (ngr <= 256) && (ws_size >= need) &&
                    ((long long)perCU * numCU >= needBlocks);

    if (fused_ok) {
        float*    ph = (float*)d_ws;
        float*    pg = ph + nh;
        unsigned* cn = (unsigned*)(pg + ng + ngr);
        (void)hipMemsetAsync(cn, 0, sizeof(unsigned), stream);
        fused_one_pass<<<needBlocks, TPB, 0, stream>>>(
            x_h, x_g, edge_attr, u, edge_idx, batch_e, W1, b1, W2, b2,
            ph, pg, cn, out, nh, ng, ngr, E, needBlocks);
    } else {
        float* ph = (float*)d_ws;
        float* pg = ph + nh;
        float* pu = pg + ng;
        int totalRows = nh + ng + ngr;
        int nb = (totalRows * 16 + TPB - 1) / TPB;
        if (nb > 2048) nb = 2048;
        precompute_partials<<<nb, TPB, 0, stream>>>(x_h, x_g, u, W1, b1,
                                                    ph, pg, pu, nh, ng, ngr);
        int eb = (E + TPB - 1) / TPB;
        edge_kernel<<<eb, TPB, 0, stream>>>(edge_idx, batch_e, edge_attr,
                                            W1, W2, b2, ph, pg, pu, out, E);
    }
}

// Round 9
// 30.042 us; speedup vs baseline: 4.9547x; 4.9547x over previous
//
#include <hip/hip_runtime.h>
#include <hip/hip_bf16.h>

// out[e] = leaky( ph[src] + pg[tgt] + pu[g] + dot(ea_e, W1[128:136]), 0.1)*W2 + b2
//   ph[i] = dot(x_h[i], W1[0:64]);  pg[j] = dot(x_g[j], W1[64:128])
//   pu[g] = dot(u[g],  W1[136:152]) + b1   (built in LDS per block in K2)
// Two dispatches, mandatory on gfx950: grid-wide sync costs >120us
// (R2: acquire-per-poll = 310us; R8: relaxed-poll + single fence = 155us --
// the release/acquire L2 writeback+invalidate on non-coherent per-XCD L2s is
// the cost, not the poll loop). No nontemporal hints (R5: +7us regression).

#define TPB 256

typedef float f32x4 __attribute__((ext_vector_type(4)));

__device__ __forceinline__ float dot4(float4 a, float4 b) {
    return a.x * b.x + a.y * b.y + a.z * b.z + a.w * b.w;
}

// K1: node partial tables only. 16 lanes/row (float4 each), 4 rows per wave
// -> 1KB contiguous per wave instruction. Branchless: two loops, weights in regs.
__global__ void __launch_bounds__(TPB, 8)
k_nodes(const float* __restrict__ xh, const float* __restrict__ xg,
        const float* __restrict__ W1,
        float* __restrict__ ph, float* __restrict__ pg,
        int nh, int ng) {
    const int gid     = blockIdx.x * TPB + threadIdx.x;
    const int group   = gid >> 4;
    const int q       = gid & 15;
    const int ngroups = (gridDim.x * TPB) >> 4;

    const float4 wh = reinterpret_cast<const float4*>(W1)[q];
    const float4 wg = reinterpret_cast<const float4*>(W1 + 64)[q];

    for (int r = group; r < nh; r += ngroups) {
        float4 v = reinterpret_cast<const float4*>(xh + (size_t)r * 64)[q];
        float s = dot4(v, wh);
        s += __shfl_xor(s, 1);
        s += __shfl_xor(s, 2);
        s += __shfl_xor(s, 4);
        s += __shfl_xor(s, 8);
        if (q == 0) ph[r] = s;
    }
    for (int r = group; r < ng; r += ngroups) {
        float4 v = reinterpret_cast<const float4*>(xg + (size_t)r * 64)[q];
        float s = dot4(v, wg);
        s += __shfl_xor(s, 1);
        s += __shfl_xor(s, 2);
        s += __shfl_xor(s, 4);
        s += __shfl_xor(s, 8);
        if (q == 0) pg[r - 0] = s;
    }
}

// K2: 4 edges/thread. pu table built in LDS per block (kills the 3rd gather).
// Gathers issued before the ea stream so their latency hides under it.
__global__ void __launch_bounds__(TPB, 8)
k_edges(const int* __restrict__ edge_index, const int* __restrict__ batch_e,
        const float* __restrict__ edge_attr, const float* __restrict__ u,
        const float* __restrict__ W1, const float* __restrict__ b1,
        const float* __restrict__ W2, const float* __restrict__ b2,
        const float* __restrict__ ph, const float* __restrict__ pg,
        float* __restrict__ out, int ngr, int E) {
    __shared__ float pu_s[256];
    if ((int)threadIdx.x < ngr) {
        const float4* uv = reinterpret_cast<const float4*>(u + (size_t)threadIdx.x * 16);
        const float4* wu = reinterpret_cast<const float4*>(W1 + 136);
        float s = dot4(uv[0], wu[0]) + dot4(uv[1], wu[1])
                + dot4(uv[2], wu[2]) + dot4(uv[3], wu[3]);
        pu_s[threadIdx.x] = s + b1[0];
    }
    __syncthreads();

    const int t = blockIdx.x * TPB + threadIdx.x;
    const int base = t * 4;
    if (base >= E) return;

    const float* wx = W1 + 128;
    const float w0 = wx[0], w1 = wx[1], w2 = wx[2], w3 = wx[3];
    const float w4 = wx[4], w5 = wx[5], w6 = wx[6], w7 = wx[7];
    const float w2s = W2[0], b2s = b2[0];

    if (base + 3 < E) {
        // index loads first, then the dependent gathers, then the ea stream
        int4 sv = *reinterpret_cast<const int4*>(edge_index + base);
        int4 tv = *reinterpret_cast<const int4*>(edge_index + E + base);
        int4 gv = *reinterpret_cast<const int4*>(batch_e + base);

        float pp[4] = {ph[sv.x], ph[sv.y], ph[sv.z], ph[sv.w]};
        float qq[4] = {pg[tv.x], pg[tv.y], pg[tv.z], pg[tv.w]};
        float rr[4] = {pu_s[gv.x], pu_s[gv.y], pu_s[gv.z], pu_s[gv.w]};

        const f32x4* eap = reinterpret_cast<const f32x4*>(edge_attr + (size_t)base * 8);
        f32x4 ea[8];
#pragma unroll
        for (int j = 0; j < 8; ++j) ea[j] = eap[j];

        f32x4 hv;
        float res[4];
#pragma unroll
        for (int i = 0; i < 4; ++i) {
            f32x4 a0 = ea[2 * i], a1 = ea[2 * i + 1];
            float h = pp[i] + qq[i] + rr[i]
                    + a0.x * w0 + a0.y * w1 + a0.z * w2 + a0.w * w3
                    + a1.x * w4 + a1.y * w5 + a1.z * w6 + a1.w * w7;
            h = (h >= 0.0f) ? h : 0.1f * h;
            res[i] = h * w2s + b2s;
        }
        hv.x = res[0]; hv.y = res[1]; hv.z = res[2]; hv.w = res[3];
        *reinterpret_cast<f32x4*>(out + base) = hv;
    } else {
        for (int e = base; e < E; ++e) {
            int s  = edge_index[e];
            int tg = edge_index[E + e];
            int g  = batch_e[e];
            const float* a = edge_attr + (size_t)e * 8;
            float h = ph[s] + pg[tg] + pu_s[g]
                    + a[0] * w0 + a[1] * w1 + a[2] * w2 + a[3] * w3
                    + a[4] * w4 + a[5] * w5 + a[6] * w6 + a[7] * w7;
            h = (h >= 0.0f) ? h : 0.1f * h;
            out[e] = h * w2s + b2s;
        }
    }
}

// Fallback if workspace too small: direct gather per edge.
__global__ void edge_fallback(const int* __restrict__ edge_index,
                              const int* __restrict__ batch_e,
                              const float* __restrict__ xh,
                              const float* __restrict__ xg,
                              const float* __restrict__ edge_attr,
                              const float* __restrict__ u,
                              const float* __restrict__ W1,
                              const float* __restrict__ b1,
                              const float* __restrict__ W2,
                              const float* __restrict__ b2,
                              float* __restrict__ out,
                              int E) {
    int e = blockIdx.x * blockDim.x + threadIdx.x;
    if (e >= E) return;
    int s = edge_index[e];
    int t = edge_index[E + e];
    int g = batch_e[e];
    float h = b1[0];
    const float* hs = xh + (size_t)s * 64;
    const float* gt = xg + (size_t)t * 64;
#pragma unroll 8
    for (int j = 0; j < 64; ++j) h += hs[j] * W1[j];
#pragma unroll 8
    for (int j = 0; j < 64; ++j) h += gt[j] * W1[64 + j];
    const float* ea = edge_attr + (size_t)e * 8;
#pragma unroll
    for (int j = 0; j < 8; ++j) h += ea[j] * W1[128 + j];
    const float* ug = u + (size_t)g * 16;
#pragma unroll
    for (int j = 0; j < 16; ++j) h += ug[j] * W1[136 + j];
    h = (h >= 0.0f) ? h : 0.1f * h;
    out[e] = h * W2[0] + b2[0];
}

extern "C" void kernel_launch(void* const* d_in, const int* in_sizes, int n_in,
                              void* d_out, int out_size, void* d_ws, size_t ws_size,
                              hipStream_t stream) {
    const float* x_h       = (const float*)d_in[0];
    const float* x_g       = (const float*)d_in[1];
    const float* edge_attr = (const float*)d_in[2];
    const float* u         = (const float*)d_in[3];
    const int*   edge_idx  = (const int*)d_in[4];
    const int*   batch_e   = (const int*)d_in[5];
    const float* W1        = (const float*)d_in[6];
    const float* b1        = (const float*)d_in[7];
    const float* W2        = (const float*)d_in[8];
    const float* b2        = (const float*)d_in[9];
    float* out = (float*)d_out;

    const int E   = in_sizes[5];        // N_EDGES
    const int nh  = in_sizes[0] / 64;   // N_H_NODES
    const int ng  = in_sizes[1] / 64;   // N_G_NODES
    const int ngr = in_sizes[3] / 16;   // N_GRAPHS

    size_t need = ((size_t)nh + ng) * sizeof(float);
    if (ws_size >= need && ngr <= 256) {
        float* ph = (float*)d_ws;
        float* pg = ph + nh;

        int maxn = (nh > ng) ? nh : ng;
        int nb = (maxn * 16 + TPB - 1) / TPB;
        if (nb > 2048) nb = 2048;
        k_nodes<<<nb, TPB, 0, stream>>>(x_h, x_g, W1, ph, pg, nh, ng);

        int threads = (E + 3) / 4;
        int eb = (threads + TPB - 1) / TPB;
        k_edges<<<eb, TPB, 0, stream>>>(edge_idx, batch_e, edge_attr, u,
                                        W1, b1, W2, b2, ph, pg, out, ngr, E);
    } else {
        int eb = (E + TPB - 1) / TPB;
        edge_fallback<<<eb, TPB, 0, stream>>>(edge_idx, batch_e, x_h, x_g, edge_attr, u,
                                              W1, b1, W2, b2, out, E);
    }
}